// Round 12
// baseline (242.238 us; speedup 1.0000x reference)
//
#include <hip/hip_runtime.h>

typedef __attribute__((ext_vector_type(8))) short s16x8;
typedef __attribute__((ext_vector_type(4))) float f32x4;

#define LN_EPS 1e-5f

__device__ __forceinline__ unsigned short f2bf(float f) {
  unsigned int u = __float_as_uint(f);
  u += 0x7fffu + ((u >> 16) & 1u);
  return (unsigned short)(u >> 16);
}

__device__ __forceinline__ unsigned cvt_pk_bf16(float lo, float hi) {
  unsigned r;
  asm("v_cvt_pk_bf16_f32 %0, %1, %2" : "=v"(r) : "v"(lo), "v"(hi));
  return r;
}

__device__ __forceinline__ float fast_exp2(float z) {
  float r; asm("v_exp_f32 %0, %1" : "=v"(r) : "v"(z)); return r;
}
__device__ __forceinline__ float fast_rcp(float z) {
  float r; asm("v_rcp_f32 %0, %1" : "=v"(r) : "v"(z)); return r;
}
__device__ __forceinline__ float fast_rsq(float z) {
  float r; asm("v_rsq_f32 %0, %1" : "=v"(r) : "v"(z)); return r;
}

// tanh-GELU via sigmoid, -2*log2(e) folded into polynomial: 7 VALU inst.
__device__ __forceinline__ float gelu_fast(float x) {
  float t = fmaf(x * x, -0.1029433f, -2.3022079f);
  float e = fast_exp2(x * t);
  return x * fast_rcp(1.0f + e);
}

// ws layout (ushort elems), fragment-major, N-sliced per wave w (frag = 1KB):
//   ws1 [0, 65536)      : GEMM1 W1^T frags,           n = w*32+nf*16+l15
//   ws2 [65536, 98304)  : GEMM2 (g1 (.) W2)^T frags,  n = w*16+l15
//   ws3 [98304, 114688) : GEMM3 (g2 (.) Wm)^T frags,  n = w*16+l15
//   f32 @114688: wl[128]  = Wm[128,:] (importance row)
//   f32 @114944: vb2[128] = sum_c be1[c] W2[c,n] + b2[n]
//   f32 @115200: vb3[128] = sum_c be2[c] Wm[c,n] + bm[n]
__global__ void prep_weights(const float* __restrict__ W1, const float* __restrict__ W2,
                             const float* __restrict__ Wm,
                             const float* __restrict__ g1, const float* __restrict__ g2,
                             unsigned short* __restrict__ ws) {
  int i = blockIdx.x * 256 + threadIdx.x;
  if (i < 65536) {
    int f = i >> 9, lane = (i >> 3) & 63, j = i & 7;
    int w = f >> 4, kk = (f >> 1) & 7, nf = f & 1;
    int n = w * 32 + nf * 16 + (lane & 15);
    int k = kk * 32 + (lane >> 4) * 8 + j;
    ws[i] = f2bf(W1[k * 256 + n]);
  } else if (i < 98304) {
    int t = i - 65536;
    int f = t >> 9, lane = (t >> 3) & 63, j = t & 7;
    int w = f >> 3, kk = f & 7;
    int n = w * 16 + (lane & 15);
    int k = kk * 32 + (lane >> 4) * 8 + j;
    ws[i] = f2bf(W2[k * 128 + n] * g1[k]);
  } else if (i < 114688) {
    int t = i - 98304;
    int f = t >> 9, lane = (t >> 3) & 63, j = t & 7;
    int w = f >> 2, kk = f & 3;
    int n = w * 16 + (lane & 15);
    int k = kk * 32 + (lane >> 4) * 8 + j;
    ws[i] = f2bf(Wm[k * 128 + n] * g2[k]);
  } else if (i < 114944) {
    int c = i - 114688;
    reinterpret_cast<float*>(ws + 114688)[c] = Wm[128 * 128 + c];
  }
}

__global__ void prep_fold(const float* __restrict__ W2, const float* __restrict__ Wm,
                          const float* __restrict__ be1, const float* __restrict__ b2,
                          const float* __restrict__ be2, const float* __restrict__ bm,
                          unsigned short* __restrict__ ws) {
  int n = threadIdx.x;  // 128
  float* f = reinterpret_cast<float*>(ws + 114944);
  float v2 = 0.f;
  for (int c = 0; c < 256; ++c) v2 = fmaf(be1[c], W2[c * 128 + n], v2);
  float v3 = 0.f;
  for (int c = 0; c < 128; ++c) v3 = fmaf(be2[c], Wm[c * 128 + n], v3);
  f[n] = v2 + b2[n];
  f[128 + n] = v3 + bm[n];
}

// 8 waves/block, 64 rows/block; waves split N; swapped-operand MFMA (lane owns a row).
// R12 = R10 structure EXACTLY (best: 226us) + gamma/beta fold only:
// H1/H2 store (x-mu)*rs; gamma pre-scaled into W2/W3; beta folded into vb2/vb3 biases.
__global__ __launch_bounds__(512, 4) void fused_edge_group(
    const float* __restrict__ emb, const int* __restrict__ eg,
    const float* __restrict__ imp,
    const float* __restrict__ b1,
    const unsigned short* __restrict__ ws,
    float* __restrict__ out, int G) {

  __shared__ __align__(16) char sh[64 * 520];    // A -> H1 (520B rows) -> H2 (264B rows)
  __shared__ __align__(16) float st[64][20];      // s at [w], q at [8+w]; 80B row stride

  const int tid = threadIdx.x;
  const int lane = tid & 63;
  const int w = tid >> 6;        // 0..7
  const int l15 = lane & 15;
  const int lgrp = lane >> 4;    // 0..3
  const int g0 = blockIdx.x * 64;

  const unsigned short* ws1w = ws + w * 8192;
  const unsigned short* ws2w = ws + 65536 + w * 4096;
  const unsigned short* ws3w = ws + 98304 + w * 2048;
  const float* fw = reinterpret_cast<const float*>(ws + 114944);

  // prefetch GEMM1 step-0 weight fragments (hides L2 latency under gather)
  s16x8 wA[2][2];
  wA[0][0] = *reinterpret_cast<const s16x8*>(ws1w + 0 * 512 + lane * 8);
  wA[0][1] = *reinterpret_cast<const s16x8*>(ws1w + 1 * 512 + lane * 8);

  // ---- gather: 64 rows x 512B f32 -> bf16 into sh rows of 520B ----
  #pragma unroll
  for (int it = 0; it < 4; ++it) {
    int s = tid + it * 512;
    int row = s >> 5, sc = s & 31;
    int g = g0 + row; if (g >= G) g = G - 1;
    int idx = eg[2 * g + (sc >> 4)];
    const float4* p = reinterpret_cast<const float4*>(emb + (size_t)idx * 128 + (sc & 15) * 8);
    float4 va = p[0], vb = p[1];
    uint4 v;
    v.x = cvt_pk_bf16(va.x, va.y); v.y = cvt_pk_bf16(va.z, va.w);
    v.z = cvt_pk_bf16(vb.x, vb.y); v.w = cvt_pk_bf16(vb.z, vb.w);
    *reinterpret_cast<uint4*>(sh + row * 520 + sc * 16) = v;
  }
  __syncthreads();

  // ---- GEMM1 (swapped): lane: row m=mt*16+l15, n = w*32+nf*16+lgrp*4+r ----
  f32x4 acc[4][2];
  #pragma unroll
  for (int mt = 0; mt < 4; ++mt) {
    acc[mt][0] = (f32x4){0.f, 0.f, 0.f, 0.f};
    acc[mt][1] = (f32x4){0.f, 0.f, 0.f, 0.f};
  }
  #pragma unroll
  for (int kk = 0; kk < 8; ++kk) {
    if (kk < 7) {
      wA[(kk + 1) & 1][0] = *reinterpret_cast<const s16x8*>(ws1w + ((kk + 1) * 2 + 0) * 512 + lane * 8);
      wA[(kk + 1) & 1][1] = *reinterpret_cast<const s16x8*>(ws1w + ((kk + 1) * 2 + 1) * 512 + lane * 8);
    }
    #pragma unroll
    for (int mt = 0; mt < 4; ++mt) {
      s16x8 xf = *reinterpret_cast<const s16x8*>(sh + (mt * 16 + l15) * 520 + kk * 64 + lgrp * 16);
      acc[mt][0] = __builtin_amdgcn_mfma_f32_16x16x32_bf16(wA[kk & 1][0], xf, acc[mt][0], 0, 0, 0);
      acc[mt][1] = __builtin_amdgcn_mfma_f32_16x16x32_bf16(wA[kk & 1][1], xf, acc[mt][1], 0, 0, 0);
    }
  }

  // prefetch GEMM2 step-0 weights (held through epilogue 1)
  s16x8 w2p = *reinterpret_cast<const s16x8*>(ws2w + lane * 8);

  // ---- epilogue1: bias+GELU, stats -> st, ONE barrier, local murs, write H1 ----
  {
    float4 b1v0 = *reinterpret_cast<const float4*>(b1 + w * 32 + lgrp * 4);
    float4 b1v1 = *reinterpret_cast<const float4*>(b1 + w * 32 + 16 + lgrp * 4);
    #pragma unroll
    for (int mt = 0; mt < 4; ++mt) {
      float s = 0.f, q = 0.f;
      #pragma unroll
      for (int r = 0; r < 4; ++r) {
        float x0 = gelu_fast(acc[mt][0][r] + ((const float*)&b1v0)[r]);
        float x1 = gelu_fast(acc[mt][1][r] + ((const float*)&b1v1)[r]);
        acc[mt][0][r] = x0; acc[mt][1][r] = x1;
        s += x0 + x1;
        q = fmaf(x0, x0, q); q = fmaf(x1, x1, q);
      }
      s += __shfl_xor(s, 16); q += __shfl_xor(q, 16);
      s += __shfl_xor(s, 32); q += __shfl_xor(q, 32);
      if (lane < 16) { st[mt * 16 + lane][w] = s; st[mt * 16 + lane][8 + w] = q; }
    }
  }
  __syncthreads();
  {
    #pragma unroll
    for (int mt = 0; mt < 4; ++mt) {
      int row = mt * 16 + l15;
      const float4* sp = reinterpret_cast<const float4*>(&st[row][0]);
      float4 sa = sp[0], sb = sp[1], qa = sp[2], qb = sp[3];
      float ssum = (sa.x + sa.y) + (sa.z + sa.w) + (sb.x + sb.y) + (sb.z + sb.w);
      float qsum = (qa.x + qa.y) + (qa.z + qa.w) + (qb.x + qb.y) + (qb.z + qb.w);
      float mu = ssum * (1.f / 256.f);
      float rs = fast_rsq(fmaf(qsum, 1.f / 256.f, -mu * mu) + LN_EPS);
      float y[8];
      #pragma unroll
      for (int r = 0; r < 4; ++r) {
        y[r]     = (acc[mt][0][r] - mu) * rs;
        y[4 + r] = (acc[mt][1][r] - mu) * rs;
      }
      uint2 p0, p1;
      p0.x = cvt_pk_bf16(y[0], y[1]); p0.y = cvt_pk_bf16(y[2], y[3]);
      p1.x = cvt_pk_bf16(y[4], y[5]); p1.y = cvt_pk_bf16(y[6], y[7]);
      char* rp = sh + row * 520 + (w * 32 + lgrp * 4) * 2;
      *reinterpret_cast<uint2*>(rp) = p0;
      *reinterpret_cast<uint2*>(rp + 32) = p1;
    }
  }
  __syncthreads();

  // ---- GEMM2 (swapped): n2 = w*16+lgrp*4+r ----
  f32x4 acc2[4];
  #pragma unroll
  for (int mt = 0; mt < 4; ++mt) acc2[mt] = (f32x4){0.f, 0.f, 0.f, 0.f};
  {
    s16x8 wB[2];
    wB[0] = w2p;
    #pragma unroll
    for (int kk = 0; kk < 8; ++kk) {
      if (kk < 7)
        wB[(kk + 1) & 1] = *reinterpret_cast<const s16x8*>(ws2w + (kk + 1) * 512 + lane * 8);
      #pragma unroll
      for (int mt = 0; mt < 4; ++mt) {
        s16x8 xf = *reinterpret_cast<const s16x8*>(sh + (mt * 16 + l15) * 520 + kk * 64 + lgrp * 16);
        acc2[mt] = __builtin_amdgcn_mfma_f32_16x16x32_bf16(wB[kk & 1], xf, acc2[mt], 0, 0, 0);
      }
    }
  }

  // prefetch GEMM3 step-0 weights (held through epilogue 2)
  s16x8 w3p = *reinterpret_cast<const s16x8*>(ws3w + lane * 8);

  // ---- epilogue2: vb2 bias + ReLU, stats, ONE barrier, local murs, write H2 ----
  {
    float4 b2v = *reinterpret_cast<const float4*>(fw + w * 16 + lgrp * 4);
    #pragma unroll
    for (int mt = 0; mt < 4; ++mt) {
      float s = 0.f, q = 0.f;
      #pragma unroll
      for (int r = 0; r < 4; ++r) {
        float x = fmaxf(acc2[mt][r] + ((const float*)&b2v)[r], 0.f);
        acc2[mt][r] = x;
        s += x; q = fmaf(x, x, q);
      }
      s += __shfl_xor(s, 16); q += __shfl_xor(q, 16);
      s += __shfl_xor(s, 32); q += __shfl_xor(q, 32);
      if (lane < 16) { st[mt * 16 + lane][w] = s; st[mt * 16 + lane][8 + w] = q; }
    }
  }
  __syncthreads();
  {
    #pragma unroll
    for (int mt = 0; mt < 4; ++mt) {
      int row = mt * 16 + l15;
      const float4* sp = reinterpret_cast<const float4*>(&st[row][0]);
      float4 sa = sp[0], sb = sp[1], qa = sp[2], qb = sp[3];
      float ssum = (sa.x + sa.y) + (sa.z + sa.w) + (sb.x + sb.y) + (sb.z + sb.w);
      float qsum = (qa.x + qa.y) + (qa.z + qa.w) + (qb.x + qb.y) + (qb.z + qb.w);
      float mu = ssum * (1.f / 128.f);
      float rs = fast_rsq(fmaf(qsum, 1.f / 128.f, -mu * mu) + LN_EPS);
      float y[4];
      #pragma unroll
      for (int r = 0; r < 4; ++r)
        y[r] = (acc2[mt][r] - mu) * rs;
      uint2 p;
      p.x = cvt_pk_bf16(y[0], y[1]); p.y = cvt_pk_bf16(y[2], y[3]);
      *reinterpret_cast<uint2*>(sh + row * 264 + (w * 16 + lgrp * 4) * 2) = p;
    }
  }
  __syncthreads();

  // ---- GEMM3 (swapped) ----
  f32x4 acc3[4];
  #pragma unroll
  for (int mt = 0; mt < 4; ++mt) acc3[mt] = (f32x4){0.f, 0.f, 0.f, 0.f};
  {
    s16x8 wC[2];
    wC[0] = w3p;
    #pragma unroll
    for (int kk = 0; kk < 4; ++kk) {
      if (kk < 3)
        wC[(kk + 1) & 1] = *reinterpret_cast<const s16x8*>(ws3w + (kk + 1) * 512 + lane * 8);
      #pragma unroll
      for (int mt = 0; mt < 4; ++mt) {
        s16x8 xf = *reinterpret_cast<const s16x8*>(sh + (mt * 16 + l15) * 264 + kk * 64 + lgrp * 16);
        acc3[mt] = __builtin_amdgcn_mfma_f32_16x16x32_bf16(wC[kk & 1], xf, acc3[mt], 0, 0, 0);
      }
    }
  }

  // ---- epilogue3: + vb3 + imp*Wm[128,:], ReLU, float4 store ----
  {
    int col0 = w * 16 + lgrp * 4;
    float4 bmv = *reinterpret_cast<const float4*>(fw + 128 + col0);
    float4 wlv = *reinterpret_cast<const float4*>(reinterpret_cast<const float*>(ws + 114688) + col0);
    #pragma unroll
    for (int mt = 0; mt < 4; ++mt) {
      int g = g0 + mt * 16 + l15;
      float impv = imp[g < G ? g : (G - 1)];
      float4 y;
      y.x = fmaxf(fmaf(impv, wlv.x, acc3[mt][0] + bmv.x), 0.f);
      y.y = fmaxf(fmaf(impv, wlv.y, acc3[mt][1] + bmv.y), 0.f);
      y.z = fmaxf(fmaf(impv, wlv.z, acc3[mt][2] + bmv.z), 0.f);
      y.w = fmaxf(fmaf(impv, wlv.w, acc3[mt][3] + bmv.w), 0.f);
      if (g < G)
        *reinterpret_cast<float4*>(out + (size_t)g * 128 + col0) = y;
    }
  }
}

extern "C" void kernel_launch(void* const* d_in, const int* in_sizes, int n_in,
                              void* d_out, int out_size, void* d_ws, size_t ws_size,
                              hipStream_t stream) {
  const float* emb = (const float*)d_in[0];
  const int* eg    = (const int*)d_in[1];
  const float* imp = (const float*)d_in[2];
  const float* W1  = (const float*)d_in[3];
  const float* b1  = (const float*)d_in[4];
  const float* g1  = (const float*)d_in[5];
  const float* be1 = (const float*)d_in[6];
  const float* W2  = (const float*)d_in[7];
  const float* b2  = (const float*)d_in[8];
  const float* g2  = (const float*)d_in[9];
  const float* be2 = (const float*)d_in[10];
  const float* Wm  = (const float*)d_in[11];
  const float* bm  = (const float*)d_in[12];
  unsigned short* ws = (unsigned short*)d_ws;
  float* out = (float*)d_out;
  int G = in_sizes[2];

  prep_weights<<<(114944 + 255) / 256, 256, 0, stream>>>(W1, W2, Wm, g1, g2, ws);
  prep_fold<<<1, 128, 0, stream>>>(W2, Wm, be1, b2, be2, bm, ws);
  int nblk = (G + 63) / 64;
  fused_edge_group<<<nblk, 512, 0, stream>>>(emb, eg, imp, b1, ws, out, G);
}

// Round 13
// 223.748 us; speedup vs baseline: 1.0826x; 1.0826x over previous
//
#include <hip/hip_runtime.h>

typedef __attribute__((ext_vector_type(8))) short s16x8;
typedef __attribute__((ext_vector_type(4))) float f32x4;

#define LN_EPS 1e-5f

__device__ __forceinline__ unsigned short f2bf(float f) {
  unsigned int u = __float_as_uint(f);
  u += 0x7fffu + ((u >> 16) & 1u);
  return (unsigned short)(u >> 16);
}

__device__ __forceinline__ unsigned cvt_pk_bf16(float lo, float hi) {
  unsigned r;
  asm("v_cvt_pk_bf16_f32 %0, %1, %2" : "=v"(r) : "v"(lo), "v"(hi));
  return r;
}

__device__ __forceinline__ float fast_exp2(float z) {
  float r; asm("v_exp_f32 %0, %1" : "=v"(r) : "v"(z)); return r;
}
__device__ __forceinline__ float fast_rcp(float z) {
  float r; asm("v_rcp_f32 %0, %1" : "=v"(r) : "v"(z)); return r;
}
__device__ __forceinline__ float fast_rsq(float z) {
  float r; asm("v_rsq_f32 %0, %1" : "=v"(r) : "v"(z)); return r;
}

// tanh-GELU via sigmoid, -2*log2(e) folded into polynomial: 7 VALU inst.
// gelu = x * rcp(1 + exp2(x*(c0 + c1*x^2)))
__device__ __forceinline__ float gelu_fast(float x) {
  float t = fmaf(x * x, -0.1029433f, -2.3022079f);
  float e = fast_exp2(x * t);
  return x * fast_rcp(1.0f + e);
}

// ws layout (ushort elems), fragment-major, N-sliced per wave w (frag = 1KB):
//   ws1 [0, 65536)      : GEMM1 W1^T frags,  n = w*32+nf*16+l15
//   ws2 [65536, 98304)  : GEMM2 W2^T frags,  n = w*16+l15
//   ws3 [98304, 114688) : GEMM3 Wm^T frags,  n = w*16+l15
//   f32 @114688: wl[128] = Wm[128,:] (importance row)
__global__ void prep_weights(const float* __restrict__ W1, const float* __restrict__ W2,
                             const float* __restrict__ Wm, unsigned short* __restrict__ ws) {
  int i = blockIdx.x * 256 + threadIdx.x;
  if (i < 65536) {
    int f = i >> 9, lane = (i >> 3) & 63, j = i & 7;
    int w = f >> 4, kk = (f >> 1) & 7, nf = f & 1;
    int n = w * 32 + nf * 16 + (lane & 15);
    int k = kk * 32 + (lane >> 4) * 8 + j;
    ws[i] = f2bf(W1[k * 256 + n]);
  } else if (i < 98304) {
    int t = i - 65536;
    int f = t >> 9, lane = (t >> 3) & 63, j = t & 7;
    int w = f >> 3, kk = f & 7;
    int n = w * 16 + (lane & 15);
    int k = kk * 32 + (lane >> 4) * 8 + j;
    ws[i] = f2bf(W2[k * 128 + n]);
  } else if (i < 114688) {
    int t = i - 98304;
    int f = t >> 9, lane = (t >> 3) & 63, j = t & 7;
    int w = f >> 2, kk = f & 3;
    int n = w * 16 + (lane & 15);
    int k = kk * 32 + (lane >> 4) * 8 + j;
    ws[i] = f2bf(Wm[k * 128 + n]);
  } else if (i < 114944) {
    int c = i - 114688;
    reinterpret_cast<float*>(ws + 114688)[c] = Wm[128 * 128 + c];
  }
}

// 8 waves/block, 64 rows/block; waves split N; swapped-operand MFMA (lane owns a row).
// R13 = R10 byte-identical revert (best measured: 226.2us).
__global__ __launch_bounds__(512, 4) void fused_edge_group(
    const float* __restrict__ emb, const int* __restrict__ eg,
    const float* __restrict__ imp,
    const float* __restrict__ b1, const float* __restrict__ g1, const float* __restrict__ be1,
    const float* __restrict__ b2, const float* __restrict__ g2, const float* __restrict__ be2,
    const float* __restrict__ bm,
    const unsigned short* __restrict__ ws,
    float* __restrict__ out, int G) {

  __shared__ __align__(16) char sh[64 * 520];    // A -> H1 (520B rows) -> H2 (264B rows)
  __shared__ __align__(16) float st[64][20];      // s at [w], q at [8+w]; 80B row stride

  const int tid = threadIdx.x;
  const int lane = tid & 63;
  const int w = tid >> 6;        // 0..7
  const int l15 = lane & 15;
  const int lgrp = lane >> 4;    // 0..3
  const int g0 = blockIdx.x * 64;

  const unsigned short* ws1w = ws + w * 8192;
  const unsigned short* ws2w = ws + 65536 + w * 4096;
  const unsigned short* ws3w = ws + 98304 + w * 2048;

  // prefetch GEMM1 step-0 weight fragments (hides L2 latency under gather)
  s16x8 wA[2][2];
  wA[0][0] = *reinterpret_cast<const s16x8*>(ws1w + 0 * 512 + lane * 8);
  wA[0][1] = *reinterpret_cast<const s16x8*>(ws1w + 1 * 512 + lane * 8);

  // ---- gather: 64 rows x 512B f32 -> bf16 into sh rows of 520B ----
  #pragma unroll
  for (int it = 0; it < 4; ++it) {
    int s = tid + it * 512;
    int row = s >> 5, sc = s & 31;
    int g = g0 + row; if (g >= G) g = G - 1;
    int idx = eg[2 * g + (sc >> 4)];
    const float4* p = reinterpret_cast<const float4*>(emb + (size_t)idx * 128 + (sc & 15) * 8);
    float4 va = p[0], vb = p[1];
    uint4 v;
    v.x = cvt_pk_bf16(va.x, va.y); v.y = cvt_pk_bf16(va.z, va.w);
    v.z = cvt_pk_bf16(vb.x, vb.y); v.w = cvt_pk_bf16(vb.z, vb.w);
    *reinterpret_cast<uint4*>(sh + row * 520 + sc * 16) = v;
  }
  __syncthreads();

  // ---- GEMM1 (swapped): lane: row m=mt*16+l15, n = w*32+nf*16+lgrp*4+r ----
  f32x4 acc[4][2];
  #pragma unroll
  for (int mt = 0; mt < 4; ++mt) {
    acc[mt][0] = (f32x4){0.f, 0.f, 0.f, 0.f};
    acc[mt][1] = (f32x4){0.f, 0.f, 0.f, 0.f};
  }
  #pragma unroll
  for (int kk = 0; kk < 8; ++kk) {
    if (kk < 7) {
      wA[(kk + 1) & 1][0] = *reinterpret_cast<const s16x8*>(ws1w + ((kk + 1) * 2 + 0) * 512 + lane * 8);
      wA[(kk + 1) & 1][1] = *reinterpret_cast<const s16x8*>(ws1w + ((kk + 1) * 2 + 1) * 512 + lane * 8);
    }
    #pragma unroll
    for (int mt = 0; mt < 4; ++mt) {
      s16x8 xf = *reinterpret_cast<const s16x8*>(sh + (mt * 16 + l15) * 520 + kk * 64 + lgrp * 16);
      acc[mt][0] = __builtin_amdgcn_mfma_f32_16x16x32_bf16(wA[kk & 1][0], xf, acc[mt][0], 0, 0, 0);
      acc[mt][1] = __builtin_amdgcn_mfma_f32_16x16x32_bf16(wA[kk & 1][1], xf, acc[mt][1], 0, 0, 0);
    }
  }

  // prefetch GEMM2 step-0 weights (held through epilogue 1)
  s16x8 w2p = *reinterpret_cast<const s16x8*>(ws2w + lane * 8);

  // ---- epilogue1: bias+GELU, stats -> st, ONE barrier, local murs, write H1 ----
  {
    float4 b1v0 = *reinterpret_cast<const float4*>(b1 + w * 32 + lgrp * 4);
    float4 b1v1 = *reinterpret_cast<const float4*>(b1 + w * 32 + 16 + lgrp * 4);
    #pragma unroll
    for (int mt = 0; mt < 4; ++mt) {
      float s = 0.f, q = 0.f;
      #pragma unroll
      for (int r = 0; r < 4; ++r) {
        float x0 = gelu_fast(acc[mt][0][r] + ((const float*)&b1v0)[r]);
        float x1 = gelu_fast(acc[mt][1][r] + ((const float*)&b1v1)[r]);
        acc[mt][0][r] = x0; acc[mt][1][r] = x1;
        s += x0 + x1;
        q = fmaf(x0, x0, q); q = fmaf(x1, x1, q);
      }
      s += __shfl_xor(s, 16); q += __shfl_xor(q, 16);
      s += __shfl_xor(s, 32); q += __shfl_xor(q, 32);
      if (lane < 16) { st[mt * 16 + lane][w] = s; st[mt * 16 + lane][8 + w] = q; }
    }
  }
  __syncthreads();
  {
    float4 g1v0 = *reinterpret_cast<const float4*>(g1 + w * 32 + lgrp * 4);
    float4 g1v1 = *reinterpret_cast<const float4*>(g1 + w * 32 + 16 + lgrp * 4);
    float4 be1v0 = *reinterpret_cast<const float4*>(be1 + w * 32 + lgrp * 4);
    float4 be1v1 = *reinterpret_cast<const float4*>(be1 + w * 32 + 16 + lgrp * 4);
    #pragma unroll
    for (int mt = 0; mt < 4; ++mt) {
      int row = mt * 16 + l15;
      const float4* sp = reinterpret_cast<const float4*>(&st[row][0]);
      float4 sa = sp[0], sb = sp[1], qa = sp[2], qb = sp[3];
      float ssum = (sa.x + sa.y) + (sa.z + sa.w) + (sb.x + sb.y) + (sb.z + sb.w);
      float qsum = (qa.x + qa.y) + (qa.z + qa.w) + (qb.x + qb.y) + (qb.z + qb.w);
      float mu = ssum * (1.f / 256.f);
      float rs = fast_rsq(fmaf(qsum, 1.f / 256.f, -mu * mu) + LN_EPS);
      float y[8];
      #pragma unroll
      for (int r = 0; r < 4; ++r) {
        y[r]     = fmaf((acc[mt][0][r] - mu) * rs, ((const float*)&g1v0)[r], ((const float*)&be1v0)[r]);
        y[4 + r] = fmaf((acc[mt][1][r] - mu) * rs, ((const float*)&g1v1)[r], ((const float*)&be1v1)[r]);
      }
      uint2 p0, p1;
      p0.x = cvt_pk_bf16(y[0], y[1]); p0.y = cvt_pk_bf16(y[2], y[3]);
      p1.x = cvt_pk_bf16(y[4], y[5]); p1.y = cvt_pk_bf16(y[6], y[7]);
      char* rp = sh + row * 520 + (w * 32 + lgrp * 4) * 2;
      *reinterpret_cast<uint2*>(rp) = p0;
      *reinterpret_cast<uint2*>(rp + 32) = p1;
    }
  }
  __syncthreads();

  // ---- GEMM2 (swapped): n2 = w*16+lgrp*4+r ----
  f32x4 acc2[4];
  #pragma unroll
  for (int mt = 0; mt < 4; ++mt) acc2[mt] = (f32x4){0.f, 0.f, 0.f, 0.f};
  {
    s16x8 wB[2];
    wB[0] = w2p;
    #pragma unroll
    for (int kk = 0; kk < 8; ++kk) {
      if (kk < 7)
        wB[(kk + 1) & 1] = *reinterpret_cast<const s16x8*>(ws2w + (kk + 1) * 512 + lane * 8);
      #pragma unroll
      for (int mt = 0; mt < 4; ++mt) {
        s16x8 xf = *reinterpret_cast<const s16x8*>(sh + (mt * 16 + l15) * 520 + kk * 64 + lgrp * 16);
        acc2[mt] = __builtin_amdgcn_mfma_f32_16x16x32_bf16(wB[kk & 1], xf, acc2[mt], 0, 0, 0);
      }
    }
  }

  // prefetch GEMM3 step-0 weights (held through epilogue 2)
  s16x8 w3p = *reinterpret_cast<const s16x8*>(ws3w + lane * 8);

  // ---- epilogue2: bias+ReLU, stats, ONE barrier, local murs, write H2 ----
  {
    float4 b2v = *reinterpret_cast<const float4*>(b2 + w * 16 + lgrp * 4);
    #pragma unroll
    for (int mt = 0; mt < 4; ++mt) {
      float s = 0.f, q = 0.f;
      #pragma unroll
      for (int r = 0; r < 4; ++r) {
        float x = fmaxf(acc2[mt][r] + ((const float*)&b2v)[r], 0.f);
        acc2[mt][r] = x;
        s += x; q = fmaf(x, x, q);
      }
      s += __shfl_xor(s, 16); q += __shfl_xor(q, 16);
      s += __shfl_xor(s, 32); q += __shfl_xor(q, 32);
      if (lane < 16) { st[mt * 16 + lane][w] = s; st[mt * 16 + lane][8 + w] = q; }
    }
  }
  __syncthreads();
  {
    float4 g2v = *reinterpret_cast<const float4*>(g2 + w * 16 + lgrp * 4);
    float4 be2v = *reinterpret_cast<const float4*>(be2 + w * 16 + lgrp * 4);
    #pragma unroll
    for (int mt = 0; mt < 4; ++mt) {
      int row = mt * 16 + l15;
      const float4* sp = reinterpret_cast<const float4*>(&st[row][0]);
      float4 sa = sp[0], sb = sp[1], qa = sp[2], qb = sp[3];
      float ssum = (sa.x + sa.y) + (sa.z + sa.w) + (sb.x + sb.y) + (sb.z + sb.w);
      float qsum = (qa.x + qa.y) + (qa.z + qa.w) + (qb.x + qb.y) + (qb.z + qb.w);
      float mu = ssum * (1.f / 128.f);
      float rs = fast_rsq(fmaf(qsum, 1.f / 128.f, -mu * mu) + LN_EPS);
      float y[4];
      #pragma unroll
      for (int r = 0; r < 4; ++r)
        y[r] = fmaf((acc2[mt][r] - mu) * rs, ((const float*)&g2v)[r], ((const float*)&be2v)[r]);
      uint2 p;
      p.x = cvt_pk_bf16(y[0], y[1]); p.y = cvt_pk_bf16(y[2], y[3]);
      *reinterpret_cast<uint2*>(sh + row * 264 + (w * 16 + lgrp * 4) * 2) = p;
    }
  }
  __syncthreads();

  // ---- GEMM3 (swapped) ----
  f32x4 acc3[4];
  #pragma unroll
  for (int mt = 0; mt < 4; ++mt) acc3[mt] = (f32x4){0.f, 0.f, 0.f, 0.f};
  {
    s16x8 wC[2];
    wC[0] = w3p;
    #pragma unroll
    for (int kk = 0; kk < 4; ++kk) {
      if (kk < 3)
        wC[(kk + 1) & 1] = *reinterpret_cast<const s16x8*>(ws3w + (kk + 1) * 512 + lane * 8);
      #pragma unroll
      for (int mt = 0; mt < 4; ++mt) {
        s16x8 xf = *reinterpret_cast<const s16x8*>(sh + (mt * 16 + l15) * 264 + kk * 64 + lgrp * 16);
        acc3[mt] = __builtin_amdgcn_mfma_f32_16x16x32_bf16(wC[kk & 1], xf, acc3[mt], 0, 0, 0);
      }
    }
  }

  // ---- epilogue3: + bm + imp*Wm[128,:], ReLU, float4 store ----
  {
    int col0 = w * 16 + lgrp * 4;
    float4 bmv = *reinterpret_cast<const float4*>(bm + col0);
    float4 wlv = *reinterpret_cast<const float4*>(reinterpret_cast<const float*>(ws + 114688) + col0);
    #pragma unroll
    for (int mt = 0; mt < 4; ++mt) {
      int g = g0 + mt * 16 + l15;
      float impv = imp[g < G ? g : (G - 1)];
      float4 y;
      y.x = fmaxf(fmaf(impv, wlv.x, acc3[mt][0] + bmv.x), 0.f);
      y.y = fmaxf(fmaf(impv, wlv.y, acc3[mt][1] + bmv.y), 0.f);
      y.z = fmaxf(fmaf(impv, wlv.z, acc3[mt][2] + bmv.z), 0.f);
      y.w = fmaxf(fmaf(impv, wlv.w, acc3[mt][3] + bmv.w), 0.f);
      if (g < G)
        *reinterpret_cast<float4*>(out + (size_t)g * 128 + col0) = y;
    }
  }
}

extern "C" void kernel_launch(void* const* d_in, const int* in_sizes, int n_in,
                              void* d_out, int out_size, void* d_ws, size_t ws_size,
                              hipStream_t stream) {
  const float* emb = (const float*)d_in[0];
  const int* eg    = (const int*)d_in[1];
  const float* imp = (const float*)d_in[2];
  const float* W1  = (const float*)d_in[3];
  const float* b1  = (const float*)d_in[4];
  const float* g1  = (const float*)d_in[5];
  const float* be1 = (const float*)d_in[6];
  const float* W2  = (const float*)d_in[7];
  const float* b2  = (const float*)d_in[8];
  const float* g2  = (const float*)d_in[9];
  const float* be2 = (const float*)d_in[10];
  const float* Wm  = (const float*)d_in[11];
  const float* bm  = (const float*)d_in[12];
  unsigned short* ws = (unsigned short*)d_ws;
  float* out = (float*)d_out;
  int G = in_sizes[2];

  prep_weights<<<(114944 + 255) / 256, 256, 0, stream>>>(W1, W2, Wm, ws);
  int nblk = (G + 63) / 64;
  fused_edge_group<<<nblk, 512, 0, stream>>>(emb, eg, imp, b1, g1, be1, b2, g2, be2, bm,
                                             ws, out, G);
}